// Round 7
// baseline (206.813 us; speedup 1.0000x reference)
//
#include <hip/hip_runtime.h>
#include <stdint.h>

#define NR 16
#define NC 80
#define NA 8400
#define NB 16
#define KPRE 1024
#define MAXDET 300
#define CONF_T 0.25f
#define IOU_THR 0.45f

// Robust scalar read: harness passes python ints most likely as int32; fall
// back to float32 reinterpretation if the int pattern is implausible.
__device__ __forceinline__ float read_dim(const void* p) {
  int iv = *(const int*)p;
  return (iv > 0 && iv < (1 << 20)) ? (float)iv : *(const float*)p;
}

__device__ __forceinline__ const float* level_ptr(const float* p0, const float* p1,
                                                  const float* p2, int a, int& HW,
                                                  int& W, float& stride, int& m) {
  if (a < 6400)      { HW = 6400; W = 80; stride = 8.f;  m = a;        return p0; }
  else if (a < 8000) { HW = 1600; W = 40; stride = 16.f; m = a - 6400; return p1; }
  else               { HW = 400;  W = 20; stride = 32.f; m = a - 8000; return p2; }
}

__device__ __forceinline__ uint64_t readlane64(uint64_t v, int lane) {
  uint32_t lo = (uint32_t)__builtin_amdgcn_readlane((int)(uint32_t)v, lane);
  uint32_t hi = (uint32_t)__builtin_amdgcn_readlane((int)(uint32_t)(v >> 32), lane);
  return ((uint64_t)hi << 32) | lo;
}

// ---------------------------------------------------------------- decode ----
// 1 thread per anchor: every channel-plane load is a 256B/wave segment.
// BW-bound at ~72MB/6.3TBps ~ 11.5us floor. FP order bit-identical to ref.
// Also zeroes the per-image done[] counters for the fused iou+scan kernel
// (stream-ordered before it; workspace is poisoned each graph replay).
__global__ __launch_bounds__(64) void k_decode(
    const float* __restrict__ p0, const float* __restrict__ p1,
    const float* __restrict__ p2, const void* __restrict__ hp,
    const void* __restrict__ wp, float4* __restrict__ boxes,
    uint32_t* __restrict__ keys, int* __restrict__ labels,
    int* __restrict__ done) {
  int aid = blockIdx.x * 64 + threadIdx.x;  // grid exactly NB*NA
  if (aid < NB) done[aid] = 0;
  int b = aid / NA, a = aid - b * NA;
  int HW, W, m; float stride;
  const float* p = level_ptr(p0, p1, p2, a, HW, W, stride, m);
  const float* base = p + (size_t)b * (4 * NR + NC) * HW + m;

  // DFL: softmax-expectation over 16 bins, each of 4 dims
  float d[4];
#pragma unroll
  for (int k = 0; k < 4; ++k) {
    const float* bk = base + (size_t)(k * NR) * HW;
    float v[NR]; float mx = -3.4e38f;
#pragma unroll
    for (int r = 0; r < NR; ++r) { v[r] = bk[(size_t)r * HW]; mx = fmaxf(mx, v[r]); }
    float se = 0.f, sn = 0.f;
#pragma unroll
    for (int r = 0; r < NR; ++r) { float e = expf(v[r] - mx); se += e; sn += e * (float)r; }
    d[k] = sn / se * stride;
  }

  // class argmax over 80 channels (raw logits; sigmoid monotone)
  const float* bc = base + (size_t)(4 * NR) * HW;
  float ml = -3.4e38f; int mc = NC;
#pragma unroll 8
  for (int ch = 0; ch < NC; ++ch) {
    float vv = bc[(size_t)ch * HW];
    if (vv > ml) { ml = vv; mc = ch; }
  }

  int y = m / W, x = m - y * W;
  float cx = ((float)x + 0.5f) * stride, cy = ((float)y + 0.5f) * stride;
  float hx = read_dim(wp) - 1.f, hy = read_dim(hp) - 1.f;
  boxes[aid] = make_float4(fminf(fmaxf(cx - d[0], 0.f), hx),
                           fminf(fmaxf(cy - d[1], 0.f), hy),
                           fminf(fmaxf(cx + d[2], 0.f), hx),
                           fminf(fmaxf(cy + d[3], 0.f), hy));
  float smax = 1.f / (1.f + expf(-ml));
  float s = smax > CONF_T ? smax : -1.0f;
  uint32_t bt = __float_as_uint(s);
  keys[aid] = (bt & 0x80000000u) ? ~bt : (bt | 0x80000000u);  // sortable
  labels[aid] = mc;
}

// --------------------- single-pass threshold + compact (per img, 16 blk) ----
// R12 lesson: do NOT distribute this across the chip (R5: +23.5us). R13 WIN
// (-8.4us): conf-passing keys have key>>16 in [0xBE80,0xBF7F] exactly, so ONE
// 256-bin histogram over key>>16 - 0xBE80 yields t16 directly (provably equal
// to the old byte3-then-byte2 radix); fallback t16=0x407F when in-range mass
// < KPRE reproduces the old path bit-for-bit.
__global__ __launch_bounds__(1024) void k_selcomp(const uint32_t* __restrict__ keys,
                                                  uint64_t* __restrict__ cmp,
                                                  int* __restrict__ ccount) {
  __shared__ __align__(16) uint32_t skeys[NA];  // 33600 B
  __shared__ uint32_t whist[16][256];           // 16 KB, one hist per wave
  __shared__ uint32_t hsum[256];
  __shared__ int s_t16, s_cnt;
  int img = blockIdx.x, tid = threadIdx.x;
  int w = tid >> 6, lane = tid & 63;
  const uint4* kb4 = (const uint4*)(keys + (size_t)img * NA);  // NA/4 = 2100
  for (int j = tid; j < NA / 4; j += 1024) ((uint4*)skeys)[j] = kb4[j];
  if (tid == 0) s_cnt = 0;
  for (int j = tid; j < 16 * 256; j += 1024) ((uint32_t*)whist)[j] = 0;
  __syncthreads();

  // ---- histogram of (key>>16) - 0xBE80 over conf-passing keys ----
  for (int j = tid; j < NA; j += 1024) {
    uint32_t k = skeys[j];
    if (k >= 0xBE800000u) atomicAdd(&whist[w][(k >> 16) - 0xBE80u], 1u);
  }
  __syncthreads();
  if (tid < 256) {
    uint32_t s = 0;
    for (int i = 0; i < 16; ++i) s += whist[i][tid];
    hsum[tid] = s;
  }
  __syncthreads();
  if (tid < 256) {
    uint32_t s = 0;
    for (int j = tid; j < 256; ++j) s += hsum[j];  // suffix sum from tid
    // unique crossing: ssuf[tid] >= KPRE && ssuf[tid+1] < KPRE
    if (s >= KPRE && (s - hsum[tid]) < KPRE) s_t16 = 0xBE80 + tid;
    if (tid == 0 && s < KPRE) s_t16 = 0x407F;  // fallback: sub-conf bin
  }
  __syncthreads();
  uint32_t t16 = (uint32_t)s_t16;

  // ---- compact: wave-aggregated slot assignment via one LDS atomic/wave ----
  for (int j0 = 0; j0 < NA; j0 += 1024) {
    int j = j0 + tid;
    uint32_t k = (j < NA) ? skeys[j] : 0;
    bool pass = (j < NA) && ((k >> 16) >= t16);
    uint64_t mask = __ballot(pass);
    int pre = __popcll(mask & ((1ull << lane) - 1ull));
    int wc = __popcll(mask);
    int base = 0;
    if (lane == 0) base = wc ? atomicAdd(&s_cnt, wc) : 0;
    base = __shfl(base, 0);
    if (pass)
      cmp[(size_t)img * NA + base + pre] =
          ((uint64_t)k << 32) | (uint64_t)(0xFFFFFFFFu - (uint32_t)j);
  }
  __syncthreads();
  if (tid == 0) ccount[img] = s_cnt;
}

// ------------------------------------------------- exact rank on top-M set --
// Compacted set == exact top-M keys (upward-closed at bin granularity), so
// local rank == global rank (order-independent: count of greater keys).
__global__ __launch_bounds__(256) void k_rank2(
    const uint64_t* __restrict__ cmp, const int* __restrict__ ccount,
    const float4* __restrict__ boxes, const int* __restrict__ labels,
    float4* __restrict__ selbox, float4* __restrict__ selboff,
    float* __restrict__ selscore, int* __restrict__ sellab) {
  __shared__ uint64_t sk[2048];
  int img = blockIdx.y;
  int M = ccount[img]; if (M > NA) M = NA;
  if (blockIdx.x * 256 >= M) return;  // uniform per block
  int c = blockIdx.x * 256 + threadIdx.x;
  uint64_t kc = (c < M) ? cmp[(size_t)img * NA + c] : 0;
  int rank = 0;
  for (int j0 = 0; j0 < M; j0 += 2048) {
    int nchunk = min(2048, M - j0);
    __syncthreads();
    for (int j = threadIdx.x; j < nchunk; j += 256)
      sk[j] = cmp[(size_t)img * NA + j0 + j];
    __syncthreads();
    if (c < M) {
      int j = 0;
      for (; j + 4 <= nchunk; j += 4) {
        rank += (int)(sk[j] > kc) + (int)(sk[j + 1] > kc) +
                (int)(sk[j + 2] > kc) + (int)(sk[j + 3] > kc);
      }
      for (; j < nchunk; ++j) rank += (int)(sk[j] > kc);
    }
  }
  if (c < M && rank < KPRE) {
    int a = (int)(0xFFFFFFFFu - (uint32_t)kc);
    uint32_t uk = (uint32_t)(kc >> 32);
    uint32_t bits = (uk & 0x80000000u) ? (uk & 0x7FFFFFFFu) : ~uk;
    float s = __uint_as_float(bits);
    int lab = labels[img * NA + a];
    float4 bx = boxes[img * NA + a];
    float off = (float)lab * 4096.0f;  // replicate reference CLS_OFFSET fp math
    int o = img * KPRE + rank;
    selbox[o] = bx;
    selboff[o] = make_float4(bx.x + off, bx.y + off, bx.z + off, bx.w + off);
    selscore[o] = s;
    sellab[o] = lab;
  }
}

// ---------------------- fused IoU bits + last-block greedy scan (per img) ---
// R14: k_scan fused into k_iou via last-block-per-image. Each image's 64
// blocks write their rowmask rows, then release (syncthreads drains stores
// via vmcnt(0) before s_barrier, + threadfence) and bump done[img]
// (device-scope atomic, guide G12/m20). The 64th block acquires (threadfence)
// and wave 0 runs the R11-proven scan verbatim. No work redistribution —
// removes one dispatch boundary and lets image i's scan overlap image j's
// iou blocks (previously separated by a chip-wide kernel boundary).
// LDS phase-reused: iou needs 20.5KB (bb+sar), scan 21.9KB (lsc+buf+keepidx).
__global__ __launch_bounds__(256) void k_iouscan(
    const float4* __restrict__ selboff, uint64_t* __restrict__ rowmask,
    int* __restrict__ done, const float4* __restrict__ selbox,
    const float* __restrict__ selscore, const int* __restrict__ sellab,
    float* __restrict__ out) {
  __shared__ __align__(16) char smem[22016];
  __shared__ int s_last;
  int img = blockIdx.y, tid = threadIdx.x;

  // ---------------- phase 1: IoU suppression bits (unchanged from R6) ------
  // rowmask[img][w][i] transposed so scan staging is coalesced. jb rotation
  // keeps the 4 concurrent bb[] b128 reads per wave on disjoint 4-bank spans.
  float4* bb = (float4*)smem;           // 16384 B
  float* sar = (float*)(smem + 16384);  // 4096 B
  for (int j = tid; j < KPRE; j += 256) {
    float4 v = selboff[img * KPRE + j];
    bb[j] = v;
    sar[j] = (v.z - v.x) * (v.w - v.y);
  }
  __syncthreads();
  {
    int i = blockIdx.x * 16 + (tid & 15);
    int w = tid >> 4;
    int rot = w & 3;
    float4 bi = bb[i];
    float ai = sar[i];
    uint64_t bits = 0;
    for (int jj = 0; jj < 64; ++jj) {
      int jb = (jj + rot) & 63;
      int j = w * 64 + jb;
      float4 bj = bb[j];
      float lx = fmaxf(bi.x, bj.x), ly = fmaxf(bi.y, bj.y);
      float rx = fminf(bi.z, bj.z), ry = fminf(bi.w, bj.w);
      float iw = fmaxf(rx - lx, 0.f), ih = fmaxf(ry - ly, 0.f);
      float inter = iw * ih;
      float aj = sar[j];
      float iou = inter / (ai + aj - inter + 1e-7f);
      bits |= (uint64_t)((iou > IOU_THR) && (j != i)) << jb;
    }
    rowmask[(size_t)img * 16384 + (size_t)w * 1024 + i] = bits;
  }

  // ---------------- completion protocol ------------------------------------
  __syncthreads();  // drains this block's rowmask stores (vmcnt(0) + barrier)
  if (tid == 0) {
    __threadfence();  // release: make stores device-visible before the add
    s_last = (atomicAdd(&done[img], 1) == (int)gridDim.x - 1);
  }
  __syncthreads();
  if (!s_last) return;
  __threadfence();  // acquire: order rowmask reads after counter observation
  if (tid >= 64) return;

  // ---------------- phase 2: greedy scan (R11-proven form, verbatim) -------
  // remv update: fixed 16-trip branchless masked OR across all 64 lanes
  // (lane l: word l&15, row-quarter l>>4); value bit-identical to serial.
  float* lsc = (float*)smem;                       // 4096 B
  uint64_t* buf = (uint64_t*)(smem + 4096);        // 2*16*65*8 = 16640 B
  int* keepidx = (int*)(smem + 4096 + 16640);      // 1200 B -> 21936
  int lane = tid;
  int wsel = lane & 15, q = lane >> 4;
  const uint64_t* g = rowmask + (size_t)img * 16384;

  for (int j = lane; j < KPRE; j += 64) lsc[j] = selscore[img * KPRE + j];

  // stage chunk 0
  {
    uint64_t r0[16];
#pragma unroll
    for (int t = 0; t < 16; ++t) r0[t] = g[t * 1024 + lane];
#pragma unroll
    for (int t = 0; t < 16; ++t) buf[t * 65 + lane] = r0[t];
  }
  asm volatile("" ::: "memory");

  uint64_t remv = 0;  // distributed: lane l holds partial of word (l&15),
                      // covering kept rows in quarter (l>>4)
  int n = 0;
  for (int c = 0; c < 16; ++c) {
    uint64_t rn[16];
    if (c + 1 < 16) {  // prefetch next chunk (global, overlapped with scan)
#pragma unroll
      for (int t = 0; t < 16; ++t) rn[t] = g[t * 1024 + (c + 1) * 64 + lane];
    }
    const uint64_t* B = buf + (c & 1) * 1040;
    uint64_t m = B[c * 65 + lane];           // self-chunk word of row `lane`
    float sc = lsc[c * 64 + lane];
    uint64_t vmask = __ballot(sc > CONF_T);  // valid (conf-passing) bitmap
    // suppressed word for this chunk = OR of the 4 quarter-partials
    uint64_t cur = readlane64(remv, c) | readlane64(remv, c + 16) |
                   readlane64(remv, c + 32) | readlane64(remv, c + 48);
    uint64_t kmask = 0;
#pragma unroll
    for (int ii = 0; ii < 64; ++ii) {
      if (((vmask >> ii) & 1ull) && !((cur >> ii) & 1ull)) {
        cur |= readlane64(m, ii);
        kmask |= (1ull << ii);
        if (lane == 0 && n < MAXDET) keepidx[n] = c * 64 + ii;
        n++;
      }
    }
    // branchless parallel remv update: 16 independent masked LDS reads/lane
    {
      uint64_t acc = 0;
#pragma unroll
      for (int t = 0; t < 16; ++t) {
        int ii = q * 16 + t;
        uint64_t msk = (uint64_t)0 - ((kmask >> ii) & 1ull);  // kept ? ~0 : 0
        acc |= B[wsel * 65 + ii] & msk;
      }
      remv |= acc;
    }
    // stop: last candidate of chunk invalid => all later invalid (sorted)
    if (!((vmask >> 63) & 1ull) || n >= MAXDET) break;
    if (c + 1 < 16) {
      uint64_t* Bn = buf + ((c + 1) & 1) * 1040;
#pragma unroll
      for (int t = 0; t < 16; ++t) Bn[t * 65 + lane] = rn[t];
    }
    asm volatile("" ::: "memory");
  }

  // parallel output pass
  asm volatile("" ::: "memory");
  float* ob = out;                        // (B,300,4)
  float* os = out + NB * MAXDET * 4;      // (B,300)
  float* ol = out + NB * MAXDET * 5;      // labels as float
  float* ov = out + NB * MAXDET * 6;      // valid as 0/1 float
  int nk = n < MAXDET ? n : MAXDET;
  for (int s0 = 0; s0 < MAXDET; s0 += 64) {
    int slot = s0 + lane;
    if (slot >= MAXDET) break;
    bool v = slot < nk;
    float4 bx = make_float4(0.f, 0.f, 0.f, 0.f);
    float scv = 0.f, lbv = -1.f;
    if (v) {
      int i = keepidx[slot];
      bx = selbox[img * KPRE + i];
      scv = lsc[i];
      lbv = (float)sellab[img * KPRE + i];
    }
    ((float4*)ob)[img * MAXDET + slot] = bx;
    os[img * MAXDET + slot] = scv;
    ol[img * MAXDET + slot] = lbv;
    ov[img * MAXDET + slot] = v ? 1.0f : 0.0f;
  }
}

// -------------------------------------------------------------- launcher ----
extern "C" void kernel_launch(void* const* d_in, const int* in_sizes, int n_in,
                              void* d_out, int out_size, void* d_ws, size_t ws_size,
                              hipStream_t stream) {
  const float* p0 = (const float*)d_in[0];
  const float* p1 = (const float*)d_in[1];
  const float* p2 = (const float*)d_in[2];
  const void* hp = d_in[3];
  const void* wp = d_in[4];

  // Workspace (~4.96 MB). rowmask ALIASES boxes: boxes is dead after
  // k_rank2's gather; k_iouscan (writer of rowmask) runs strictly after.
  char* ws = (char*)d_ws;
  float4*   boxes    = (float4*)(ws + 0);          // 2150400
  uint64_t* rowmask  = (uint64_t*)(ws + 0);        // alias: 2097152
  uint32_t* keys     = (uint32_t*)(ws + 2150400);  // 537600
  int*      labels   = (int*)(ws + 2688000);       // 537600
  float4*   selbox   = (float4*)(ws + 3225600);    // 262144
  float4*   selboff  = (float4*)(ws + 3487744);    // 262144
  float*    selscore = (float*)(ws + 3749888);     // 65536
  int*      sellab   = (int*)(ws + 3815424);       // 65536
  int*      ccount   = (int*)(ws + 3880960);       // 64
  uint64_t* cmp      = (uint64_t*)(ws + 3881024);  // 1075200 -> 4956224
  int*      done     = (int*)(ws + 4956224);       // 64 -> end 4956288

  k_decode<<<(NB * NA) / 64, 64, 0, stream>>>(p0, p1, p2, hp, wp,
                                              boxes, keys, labels, done);
  k_selcomp<<<NB, 1024, 0, stream>>>(keys, cmp, ccount);
  dim3 rg((NA + 255) / 256, NB);
  k_rank2<<<rg, 256, 0, stream>>>(cmp, ccount, boxes, labels,
                                  selbox, selboff, selscore, sellab);
  dim3 ig(KPRE / 16, NB);
  k_iouscan<<<ig, 256, 0, stream>>>(selboff, rowmask, done,
                                    selbox, selscore, sellab, (float*)d_out);
}

// Round 8
// 185.773 us; speedup vs baseline: 1.1133x; 1.1133x over previous
//
#include <hip/hip_runtime.h>
#include <stdint.h>

#define NR 16
#define NC 80
#define NA 8400
#define NB 16
#define KPRE 1024
#define MAXDET 300
#define CONF_T 0.25f
#define IOU_THR 0.45f

// Robust scalar read: harness passes python ints most likely as int32; fall
// back to float32 reinterpretation if the int pattern is implausible.
__device__ __forceinline__ float read_dim(const void* p) {
  int iv = *(const int*)p;
  return (iv > 0 && iv < (1 << 20)) ? (float)iv : *(const float*)p;
}

__device__ __forceinline__ const float* level_ptr(const float* p0, const float* p1,
                                                  const float* p2, int a, int& HW,
                                                  int& W, float& stride, int& m) {
  if (a < 6400)      { HW = 6400; W = 80; stride = 8.f;  m = a;        return p0; }
  else if (a < 8000) { HW = 1600; W = 40; stride = 16.f; m = a - 6400; return p1; }
  else               { HW = 400;  W = 20; stride = 32.f; m = a - 8000; return p2; }
}

__device__ __forceinline__ uint64_t readlane64(uint64_t v, int lane) {
  uint32_t lo = (uint32_t)__builtin_amdgcn_readlane((int)(uint32_t)v, lane);
  uint32_t hi = (uint32_t)__builtin_amdgcn_readlane((int)(uint32_t)(v >> 32), lane);
  return ((uint64_t)hi << 32) | lo;
}

// ---------------------------------------------------------------- decode ----
// 1 thread per anchor: every channel-plane load is a 256B/wave segment.
// BW-bound at ~72MB/6.3TBps ~ 11.5us floor. FP order bit-identical to ref.
__global__ __launch_bounds__(64) void k_decode(
    const float* __restrict__ p0, const float* __restrict__ p1,
    const float* __restrict__ p2, const void* __restrict__ hp,
    const void* __restrict__ wp, float4* __restrict__ boxes,
    uint32_t* __restrict__ keys, int* __restrict__ labels) {
  int aid = blockIdx.x * 64 + threadIdx.x;  // grid exactly NB*NA
  int b = aid / NA, a = aid - b * NA;
  int HW, W, m; float stride;
  const float* p = level_ptr(p0, p1, p2, a, HW, W, stride, m);
  const float* base = p + (size_t)b * (4 * NR + NC) * HW + m;

  // DFL: softmax-expectation over 16 bins, each of 4 dims
  float d[4];
#pragma unroll
  for (int k = 0; k < 4; ++k) {
    const float* bk = base + (size_t)(k * NR) * HW;
    float v[NR]; float mx = -3.4e38f;
#pragma unroll
    for (int r = 0; r < NR; ++r) { v[r] = bk[(size_t)r * HW]; mx = fmaxf(mx, v[r]); }
    float se = 0.f, sn = 0.f;
#pragma unroll
    for (int r = 0; r < NR; ++r) { float e = expf(v[r] - mx); se += e; sn += e * (float)r; }
    d[k] = sn / se * stride;
  }

  // class argmax over 80 channels (raw logits; sigmoid monotone)
  const float* bc = base + (size_t)(4 * NR) * HW;
  float ml = -3.4e38f; int mc = NC;
#pragma unroll 8
  for (int ch = 0; ch < NC; ++ch) {
    float vv = bc[(size_t)ch * HW];
    if (vv > ml) { ml = vv; mc = ch; }
  }

  int y = m / W, x = m - y * W;
  float cx = ((float)x + 0.5f) * stride, cy = ((float)y + 0.5f) * stride;
  float hx = read_dim(wp) - 1.f, hy = read_dim(hp) - 1.f;
  boxes[aid] = make_float4(fminf(fmaxf(cx - d[0], 0.f), hx),
                           fminf(fmaxf(cy - d[1], 0.f), hy),
                           fminf(fmaxf(cx + d[2], 0.f), hx),
                           fminf(fmaxf(cy + d[3], 0.f), hy));
  float smax = 1.f / (1.f + expf(-ml));
  float s = smax > CONF_T ? smax : -1.0f;
  uint32_t bt = __float_as_uint(s);
  keys[aid] = (bt & 0x80000000u) ? ~bt : (bt | 0x80000000u);  // sortable
  labels[aid] = mc;
}

// --------------------- single-pass threshold + compact (per img, 16 blk) ----
// R12 lesson: do NOT distribute this across the chip (R5: +23.5us). R13 WIN
// (-8.4us): conf-passing keys have key>>16 in [0xBE80,0xBF7F] exactly, so ONE
// 256-bin histogram over key>>16 - 0xBE80 yields t16 directly (provably equal
// to the old byte3-then-byte2 radix); fallback t16=0x407F when in-range mass
// < KPRE reproduces the old path bit-for-bit.
__global__ __launch_bounds__(1024) void k_selcomp(const uint32_t* __restrict__ keys,
                                                  uint64_t* __restrict__ cmp,
                                                  int* __restrict__ ccount) {
  __shared__ __align__(16) uint32_t skeys[NA];  // 33600 B
  __shared__ uint32_t whist[16][256];           // 16 KB, one hist per wave
  __shared__ uint32_t hsum[256];
  __shared__ int s_t16, s_cnt;
  int img = blockIdx.x, tid = threadIdx.x;
  int w = tid >> 6, lane = tid & 63;
  const uint4* kb4 = (const uint4*)(keys + (size_t)img * NA);  // NA/4 = 2100
  for (int j = tid; j < NA / 4; j += 1024) ((uint4*)skeys)[j] = kb4[j];
  if (tid == 0) s_cnt = 0;
  for (int j = tid; j < 16 * 256; j += 1024) ((uint32_t*)whist)[j] = 0;
  __syncthreads();

  // ---- histogram of (key>>16) - 0xBE80 over conf-passing keys ----
  for (int j = tid; j < NA; j += 1024) {
    uint32_t k = skeys[j];
    if (k >= 0xBE800000u) atomicAdd(&whist[w][(k >> 16) - 0xBE80u], 1u);
  }
  __syncthreads();
  if (tid < 256) {
    uint32_t s = 0;
    for (int i = 0; i < 16; ++i) s += whist[i][tid];
    hsum[tid] = s;
  }
  __syncthreads();
  if (tid < 256) {
    uint32_t s = 0;
    for (int j = tid; j < 256; ++j) s += hsum[j];  // suffix sum from tid
    // unique crossing: ssuf[tid] >= KPRE && ssuf[tid+1] < KPRE
    if (s >= KPRE && (s - hsum[tid]) < KPRE) s_t16 = 0xBE80 + tid;
    if (tid == 0 && s < KPRE) s_t16 = 0x407F;  // fallback: sub-conf bin
  }
  __syncthreads();
  uint32_t t16 = (uint32_t)s_t16;

  // ---- compact: wave-aggregated slot assignment via one LDS atomic/wave ----
  for (int j0 = 0; j0 < NA; j0 += 1024) {
    int j = j0 + tid;
    uint32_t k = (j < NA) ? skeys[j] : 0;
    bool pass = (j < NA) && ((k >> 16) >= t16);
    uint64_t mask = __ballot(pass);
    int pre = __popcll(mask & ((1ull << lane) - 1ull));
    int wc = __popcll(mask);
    int base = 0;
    if (lane == 0) base = wc ? atomicAdd(&s_cnt, wc) : 0;
    base = __shfl(base, 0);
    if (pass)
      cmp[(size_t)img * NA + base + pre] =
          ((uint64_t)k << 32) | (uint64_t)(0xFFFFFFFFu - (uint32_t)j);
  }
  __syncthreads();
  if (tid == 0) ccount[img] = s_cnt;
}

// ------------------------------------------------- exact rank on top-M set --
// Compacted set == exact top-M keys (upward-closed at bin granularity), so
// local rank == global rank (order-independent: count of greater keys).
__global__ __launch_bounds__(256) void k_rank2(
    const uint64_t* __restrict__ cmp, const int* __restrict__ ccount,
    const float4* __restrict__ boxes, const int* __restrict__ labels,
    float4* __restrict__ selbox, float4* __restrict__ selboff,
    float* __restrict__ selscore, int* __restrict__ sellab) {
  __shared__ uint64_t sk[2048];
  int img = blockIdx.y;
  int M = ccount[img]; if (M > NA) M = NA;
  if (blockIdx.x * 256 >= M) return;  // uniform per block
  int c = blockIdx.x * 256 + threadIdx.x;
  uint64_t kc = (c < M) ? cmp[(size_t)img * NA + c] : 0;
  int rank = 0;
  for (int j0 = 0; j0 < M; j0 += 2048) {
    int nchunk = min(2048, M - j0);
    __syncthreads();
    for (int j = threadIdx.x; j < nchunk; j += 256)
      sk[j] = cmp[(size_t)img * NA + j0 + j];
    __syncthreads();
    if (c < M) {
      int j = 0;
      for (; j + 4 <= nchunk; j += 4) {
        rank += (int)(sk[j] > kc) + (int)(sk[j + 1] > kc) +
                (int)(sk[j + 2] > kc) + (int)(sk[j + 3] > kc);
      }
      for (; j < nchunk; ++j) rank += (int)(sk[j] > kc);
    }
  }
  if (c < M && rank < KPRE) {
    int a = (int)(0xFFFFFFFFu - (uint32_t)kc);
    uint32_t uk = (uint32_t)(kc >> 32);
    uint32_t bits = (uk & 0x80000000u) ? (uk & 0x7FFFFFFFu) : ~uk;
    float s = __uint_as_float(bits);
    int lab = labels[img * NA + a];
    float4 bx = boxes[img * NA + a];
    float off = (float)lab * 4096.0f;  // replicate reference CLS_OFFSET fp math
    int o = img * KPRE + rank;
    selbox[o] = bx;
    selboff[o] = make_float4(bx.x + off, bx.y + off, bx.z + off, bx.w + off);
    selscore[o] = s;
    sellab[o] = lab;
  }
}

// ----------------------------------------------------- IoU suppression bits -
// R14 lesson: do NOT fuse the scan into this kernel via last-block-per-image
// (R7: 67-69us fused vs ~11us split — the consuming block pays cross-XCD
// coherence latency on its serial critical path; a kernel boundary is CHEAPER
// than device-scope producer-consumer handoff on MI355X).
// Output layout TRANSPOSED: rowmask[img][w][i] (w=word 0..15, i=row 0..1023)
// so k_scan's per-chunk staging loads are coalesced.
// Inner loop rotated per wave-quarter: jb = (jj + (w&3)) & 63 keeps the 4
// concurrent bb[] b128 reads on disjoint 4-bank spans -> conflict-free.
// Areas precomputed into sar[] (bit-identical expression; broadcast read).
__global__ __launch_bounds__(256) void k_iou(const float4* __restrict__ selboff,
                                             uint64_t* __restrict__ rowmask) {
  __shared__ float4 bb[KPRE];
  __shared__ float sar[KPRE];
  int img = blockIdx.y;
  for (int j = threadIdx.x; j < KPRE; j += 256) {
    float4 v = selboff[img * KPRE + j];
    bb[j] = v;
    sar[j] = (v.z - v.x) * (v.w - v.y);
  }
  __syncthreads();
  int i = blockIdx.x * 16 + (threadIdx.x & 15);
  int w = threadIdx.x >> 4;
  int rot = w & 3;
  float4 bi = bb[i];
  float ai = sar[i];
  uint64_t bits = 0;
  for (int jj = 0; jj < 64; ++jj) {
    int jb = (jj + rot) & 63;
    int j = w * 64 + jb;
    float4 bj = bb[j];
    float lx = fmaxf(bi.x, bj.x), ly = fmaxf(bi.y, bj.y);
    float rx = fminf(bi.z, bj.z), ry = fminf(bi.w, bj.w);
    float iw = fmaxf(rx - lx, 0.f), ih = fmaxf(ry - ly, 0.f);
    float inter = iw * ih;
    float aj = sar[j];
    float iou = inter / (ai + aj - inter + 1e-7f);
    bits |= (uint64_t)((iou > IOU_THR) && (j != i)) << jb;
  }
  rowmask[(size_t)img * 16384 + (size_t)w * 1024 + i] = bits;
}

// --------------------------- single-wave barrier-free greedy scan (SALU) ----
// R11 WIN (-13.4us): remv update is a fixed 16-trip branchless masked OR
// across all 64 lanes (lane l: word l&15, row-quarter l>>4) — 16 independent
// ds_read_b64 pipeline under counted lgkmcnt, vs R0's serial ffs-walk
// (ds_read -> lgkmcnt(0) -> v_or per kept row). remv value bit-identical.
// Do not re-modify without per-kernel timing evidence (R2 lesson).
__global__ __launch_bounds__(64) void k_scan(
    const uint64_t* __restrict__ rowmask, const float4* __restrict__ selbox,
    const float* __restrict__ selscore, const int* __restrict__ sellab,
    float* __restrict__ out) {
  __shared__ float lsc[KPRE];
  __shared__ uint64_t buf[2][16 * 65];  // [w*65+ii], pad avoids bank conflicts
  __shared__ int keepidx[MAXDET];
  int img = blockIdx.x, lane = threadIdx.x;
  int wsel = lane & 15, q = lane >> 4;
  const uint64_t* g = rowmask + (size_t)img * 16384;

  for (int j = lane; j < KPRE; j += 64) lsc[j] = selscore[img * KPRE + j];

  // stage chunk 0
  {
    uint64_t r0[16];
#pragma unroll
    for (int t = 0; t < 16; ++t) r0[t] = g[t * 1024 + lane];
#pragma unroll
    for (int t = 0; t < 16; ++t) buf[0][t * 65 + lane] = r0[t];
  }
  asm volatile("" ::: "memory");

  uint64_t remv = 0;  // distributed: lane l holds partial of word (l&15),
                      // covering kept rows in quarter (l>>4)
  int n = 0;
  for (int c = 0; c < 16; ++c) {
    uint64_t rn[16];
    if (c + 1 < 16) {  // prefetch next chunk (global, overlapped with scan)
#pragma unroll
      for (int t = 0; t < 16; ++t) rn[t] = g[t * 1024 + (c + 1) * 64 + lane];
    }
    const uint64_t* B = buf[c & 1];
    uint64_t m = B[c * 65 + lane];           // self-chunk word of row `lane`
    float sc = lsc[c * 64 + lane];
    uint64_t vmask = __ballot(sc > CONF_T);  // valid (conf-passing) bitmap
    // suppressed word for this chunk = OR of the 4 quarter-partials
    uint64_t cur = readlane64(remv, c) | readlane64(remv, c + 16) |
                   readlane64(remv, c + 32) | readlane64(remv, c + 48);
    uint64_t kmask = 0;
#pragma unroll
    for (int ii = 0; ii < 64; ++ii) {
      if (((vmask >> ii) & 1ull) && !((cur >> ii) & 1ull)) {
        cur |= readlane64(m, ii);
        kmask |= (1ull << ii);
        if (lane == 0 && n < MAXDET) keepidx[n] = c * 64 + ii;
        n++;
      }
    }
    // branchless parallel remv update: 16 independent masked LDS reads/lane
    {
      uint64_t acc = 0;
#pragma unroll
      for (int t = 0; t < 16; ++t) {
        int ii = q * 16 + t;
        uint64_t msk = (uint64_t)0 - ((kmask >> ii) & 1ull);  // kept ? ~0 : 0
        acc |= B[wsel * 65 + ii] & msk;
      }
      remv |= acc;
    }
    // stop: last candidate of chunk invalid => all later invalid (sorted)
    if (!((vmask >> 63) & 1ull) || n >= MAXDET) break;
    if (c + 1 < 16) {
#pragma unroll
      for (int t = 0; t < 16; ++t) buf[(c + 1) & 1][t * 65 + lane] = rn[t];
    }
    asm volatile("" ::: "memory");
  }

  // parallel output pass
  asm volatile("" ::: "memory");
  float* ob = out;                        // (B,300,4)
  float* os = out + NB * MAXDET * 4;      // (B,300)
  float* ol = out + NB * MAXDET * 5;      // labels as float
  float* ov = out + NB * MAXDET * 6;      // valid as 0/1 float
  int nk = n < MAXDET ? n : MAXDET;
  for (int s0 = 0; s0 < MAXDET; s0 += 64) {
    int slot = s0 + lane;
    if (slot >= MAXDET) break;
    bool v = slot < nk;
    float4 bx = make_float4(0.f, 0.f, 0.f, 0.f);
    float scv = 0.f, lbv = -1.f;
    if (v) {
      int i = keepidx[slot];
      bx = selbox[img * KPRE + i];
      scv = lsc[i];
      lbv = (float)sellab[img * KPRE + i];
    }
    ((float4*)ob)[img * MAXDET + slot] = bx;
    os[img * MAXDET + slot] = scv;
    ol[img * MAXDET + slot] = lbv;
    ov[img * MAXDET + slot] = v ? 1.0f : 0.0f;
  }
}

// -------------------------------------------------------------- launcher ----
extern "C" void kernel_launch(void* const* d_in, const int* in_sizes, int n_in,
                              void* d_out, int out_size, void* d_ws, size_t ws_size,
                              hipStream_t stream) {
  const float* p0 = (const float*)d_in[0];
  const float* p1 = (const float*)d_in[1];
  const float* p2 = (const float*)d_in[2];
  const void* hp = d_in[3];
  const void* wp = d_in[4];

  // Workspace (~4.96 MB). rowmask ALIASES boxes: boxes is dead after
  // k_rank2's gather; k_iou (writer of rowmask) runs strictly after.
  char* ws = (char*)d_ws;
  float4*   boxes    = (float4*)(ws + 0);          // 2150400
  uint64_t* rowmask  = (uint64_t*)(ws + 0);        // alias: 2097152
  uint32_t* keys     = (uint32_t*)(ws + 2150400);  // 537600
  int*      labels   = (int*)(ws + 2688000);       // 537600
  float4*   selbox   = (float4*)(ws + 3225600);    // 262144
  float4*   selboff  = (float4*)(ws + 3487744);    // 262144
  float*    selscore = (float*)(ws + 3749888);     // 65536
  int*      sellab   = (int*)(ws + 3815424);       // 65536
  int*      ccount   = (int*)(ws + 3880960);       // 64
  uint64_t* cmp      = (uint64_t*)(ws + 3881024);  // 1075200 -> end 4956224

  k_decode<<<(NB * NA) / 64, 64, 0, stream>>>(p0, p1, p2, hp, wp,
                                              boxes, keys, labels);
  k_selcomp<<<NB, 1024, 0, stream>>>(keys, cmp, ccount);
  dim3 rg((NA + 255) / 256, NB);
  k_rank2<<<rg, 256, 0, stream>>>(cmp, ccount, boxes, labels,
                                  selbox, selboff, selscore, sellab);
  dim3 ig(KPRE / 16, NB);
  k_iou<<<ig, 256, 0, stream>>>(selboff, rowmask);
  k_scan<<<NB, 64, 0, stream>>>(rowmask, selbox, selscore, sellab,
                                (float*)d_out);
}